// Round 1
// baseline (404.618 us; speedup 1.0000x reference)
//
#include <hip/hip_runtime.h>

// GraphSAGE 2-layer + linear head, N=50000, E=600000, C=128 everywhere.
// Pipeline:
//   CSR build (deg -> scan -> fill)   [int atomics only, 600k each]
//   x -> fp16
//   per layer: wave-per-node mean-aggregate (fp32 accum, fp16 in/out)
//              MFMA fp16 GEMM  Y = act([U|V] @ [Wl;Wr]^T-staged + b)
// All matmuls use mfma_f32_16x16x32_f16 with W pre-transposed to [N][K] fp16
// so A and B fragments are single 16B contiguous global loads (no LDS).

typedef _Float16 f16;
typedef __attribute__((ext_vector_type(2))) _Float16 f16x2;
typedef __attribute__((ext_vector_type(4))) _Float16 f16x4;
typedef __attribute__((ext_vector_type(8))) _Float16 f16x8;
typedef __attribute__((ext_vector_type(4))) float f32x4;

__global__ void convert_f32_to_f16(const float* __restrict__ in, f16* __restrict__ out, int n4) {
  int i = blockIdx.x * blockDim.x + threadIdx.x;
  if (i < n4) {
    const float4 v = ((const float4*)in)[i];
    f16x4 h = { (f16)v.x, (f16)v.y, (f16)v.z, (f16)v.w };
    ((f16x4*)out)[i] = h;
  }
}

// wt[n*256 + k] = (k<128 ? WA[k][n] : WB[k-128][n]) as fp16.  [K=256 rows stacked]
__global__ void prep_w(const float* __restrict__ WA, const float* __restrict__ WB,
                       f16* __restrict__ wt) {
  int tid = blockIdx.x * blockDim.x + threadIdx.x;
  if (tid < 256 * 128) {
    int n = tid & 127, k = tid >> 7;
    float v = (k < 128) ? WA[k * 128 + n] : WB[(k - 128) * 128 + n];
    wt[n * 256 + k] = (f16)v;
  }
}

__global__ void deg_kernel(const int* __restrict__ ei, int* __restrict__ deg, int E) {
  int e = blockIdx.x * blockDim.x + threadIdx.x;
  if (e < E) atomicAdd(&deg[ei[E + e]], 1);
}

// exclusive scan, 1024-elem chunks per block (Hillis-Steele, ping-pong LDS)
__global__ void scan_block_kernel(const int* __restrict__ in, int* __restrict__ out,
                                  int* __restrict__ sums, int n) {
  __shared__ int s[2][1024];
  int t = threadIdx.x;
  int gid = blockIdx.x * 1024 + t;
  int v = (gid < n) ? in[gid] : 0;
  int cur = 0;
  s[0][t] = v;
  __syncthreads();
  for (int ofs = 1; ofs < 1024; ofs <<= 1) {
    int nv = s[cur][t] + ((t >= ofs) ? s[cur][t - ofs] : 0);
    s[cur ^ 1][t] = nv;
    cur ^= 1;
    __syncthreads();
  }
  if (gid < n) out[gid] = s[cur][t] - v;      // exclusive within block
  if (t == 1023) sums[blockIdx.x] = s[cur][1023];
}

// single-wave shuffle scan of block sums (nb <= 64; N=50000 -> nb=49)
__global__ void scan_sums_kernel(int* __restrict__ sums, int nb, int* __restrict__ off, int n) {
  int lane = threadIdx.x;
  int orig = (lane < nb) ? sums[lane] : 0;
  int v = orig;
  for (int ofs = 1; ofs < 64; ofs <<= 1) {
    int u = __shfl_up(v, ofs);
    if (lane >= ofs) v += u;
  }
  if (lane < nb) sums[lane] = v - orig;       // exclusive block offsets
  if (lane == nb - 1) off[n] = v;             // total == E
}

__global__ void scan_add_kernel(int* __restrict__ off, const int* __restrict__ sums, int n) {
  int gid = blockIdx.x * 1024 + threadIdx.x;
  if (gid < n) off[gid] += sums[blockIdx.x];
}

__global__ void fill_kernel(const int* __restrict__ ei, const int* __restrict__ off,
                            int* __restrict__ cursor, int* __restrict__ srcs, int E) {
  int e = blockIdx.x * blockDim.x + threadIdx.x;
  if (e < E) {
    int src = ei[e], dst = ei[E + e];
    int pos = atomicAdd(&cursor[dst], 1);
    srcs[off[dst] + pos] = src;
  }
}

// one wave per node: lane handles 2 channels; coalesced 256B row reads
__global__ void aggregate_kernel(const f16* __restrict__ feat, const int* __restrict__ off,
                                 const int* __restrict__ srcs, f16* __restrict__ meanf, int n) {
  int wid = (int)((blockIdx.x * blockDim.x + threadIdx.x) >> 6);
  int lane = threadIdx.x & 63;
  if (wid >= n) return;
  int beg = off[wid], end = off[wid + 1];
  float a0 = 0.f, a1 = 0.f;
  for (int e = beg; e < end; ++e) {
    int s = srcs[e];
    f16x2 v = *(const f16x2*)(feat + (size_t)s * 128 + lane * 2);
    a0 += (float)v.x;
    a1 += (float)v.y;
  }
  float inv = 1.0f / fmaxf((float)(end - beg), 1.0f);
  f16x2 o = { (f16)(a0 * inv), (f16)(a1 * inv) };
  *(f16x2*)(meanf + (size_t)wid * 128 + lane * 2) = o;
}

// Y[M,128] = act([U|V][M,256] @ W + bias); W staged transposed as wt[n][k] fp16.
// block = 256 thr = 4 waves; wave computes 16 rows x 128 cols.
// A frag:  lane m=lane&15, k=(lane>>4)*8+j  -> 16B contiguous load from U/V row
// B frag:  lane n=lane&15, k=(lane>>4)*8+j  -> 16B contiguous load from wt row
// C/D:     col=lane&15, row=(lane>>4)*4+reg
template <bool RELU, bool OUT16>
__global__ __launch_bounds__(256) void gemm_kernel(
    const f16* __restrict__ U, const f16* __restrict__ V, const f16* __restrict__ Wt,
    const float* __restrict__ bias, void* __restrict__ outp, int M) {
  int wave = threadIdx.x >> 6;
  int lane = threadIdx.x & 63;
  int m0 = blockIdx.x * 64 + wave * 16;
  int row = m0 + (lane & 15);
  int rowc = row < M ? row : M - 1;   // clamp tail-row loads (stores guarded)
  int kq = (lane >> 4) * 8;
  const f16* baseU = U + (size_t)rowc * 128 + kq;
  const f16* baseV = V + (size_t)rowc * 128 + kq;
  const f16* baseW = Wt + (size_t)(lane & 15) * 256 + kq;
  f32x4 acc[8] = {};
#pragma unroll
  for (int kk = 0; kk < 8; ++kk) {
    const int k0 = kk * 32;
    const f16* ap = (k0 < 128) ? (baseU + k0) : (baseV + (k0 - 128));
    f16x8 a = *(const f16x8*)ap;
#pragma unroll
    for (int t = 0; t < 8; ++t) {
      f16x8 b = *(const f16x8*)(baseW + t * 16 * 256 + k0);
      acc[t] = __builtin_amdgcn_mfma_f32_16x16x32_f16(a, b, acc[t], 0, 0, 0);
    }
  }
  int col = lane & 15;
  int rbase = m0 + (lane >> 4) * 4;
#pragma unroll
  for (int t = 0; t < 8; ++t) {
    float bv = bias[t * 16 + col];
#pragma unroll
    for (int i = 0; i < 4; ++i) {
      int r = rbase + i;
      if (r < M) {
        float v = acc[t][i] + bv;
        if (RELU) v = fmaxf(v, 0.f);
        size_t idx = (size_t)r * 128 + t * 16 + col;
        if (OUT16) ((f16*)outp)[idx] = (f16)v;
        else       ((float*)outp)[idx] = v;
      }
    }
  }
}

extern "C" void kernel_launch(void* const* d_in, const int* in_sizes, int n_in,
                              void* d_out, int out_size, void* d_ws, size_t ws_size,
                              hipStream_t stream) {
  (void)n_in; (void)out_size; (void)ws_size;
  const float* x    = (const float*)d_in[0];
  const int*   ei   = (const int*)d_in[1];
  const float* W1l  = (const float*)d_in[2];
  const float* b1l  = (const float*)d_in[3];
  const float* W1r  = (const float*)d_in[4];
  const float* W2l  = (const float*)d_in[5];
  const float* b2l  = (const float*)d_in[6];
  const float* W2r  = (const float*)d_in[7];
  const float* Wlin = (const float*)d_in[8];
  const float* blin = (const float*)d_in[9];
  const int N = in_sizes[0] / 128;
  const int E = in_sizes[1] / 2;

  char* ws = (char*)d_ws;
  size_t o = 0;
  auto alloc = [&](size_t bytes) {
    char* p = ws + o;
    o = (o + bytes + 255) & ~(size_t)255;
    return p;
  };
  f16* xh   = (f16*)alloc((size_t)N * 128 * 2);
  f16* x1h  = (f16*)alloc((size_t)N * 128 * 2);
  f16* x2h  = (f16*)alloc((size_t)N * 128 * 2);
  f16* mh   = (f16*)alloc((size_t)N * 128 * 2);
  f16* wt1  = (f16*)alloc(256 * 128 * 2);
  f16* wt2  = (f16*)alloc(256 * 128 * 2);
  f16* wt3  = (f16*)alloc(256 * 128 * 2);
  int* deg  = (int*)alloc((size_t)N * 4);
  int* off  = (int*)alloc(((size_t)N + 1) * 4);
  int* cur  = (int*)alloc((size_t)N * 4);
  int* srcs = (int*)alloc((size_t)E * 4);
  int* sums = (int*)alloc(64 * 4);

  hipMemsetAsync(deg, 0, (size_t)N * 4, stream);
  hipMemsetAsync(cur, 0, (size_t)N * 4, stream);

  const int nb = (N + 1023) / 1024;  // 49 for N=50000 (must be <= 64)
  deg_kernel<<<(E + 255) / 256, 256, 0, stream>>>(ei, deg, E);
  scan_block_kernel<<<nb, 1024, 0, stream>>>(deg, off, sums, N);
  scan_sums_kernel<<<1, 64, 0, stream>>>(sums, nb, off, N);
  scan_add_kernel<<<nb, 1024, 0, stream>>>(off, sums, N);
  fill_kernel<<<(E + 255) / 256, 256, 0, stream>>>(ei, off, cur, srcs, E);

  convert_f32_to_f16<<<((N * 128 / 4) + 255) / 256, 256, 0, stream>>>(x, xh, N * 128 / 4);
  prep_w<<<(256 * 128 + 255) / 256, 256, 0, stream>>>(W1l, W1r, wt1);
  prep_w<<<(256 * 128 + 255) / 256, 256, 0, stream>>>(W2l, W2r, wt2);
  prep_w<<<(256 * 128 + 255) / 256, 256, 0, stream>>>(Wlin, Wlin + 128 * 128, wt3);

  const int aggBlocks  = (N + 3) / 4;    // 4 waves/block, wave per node
  const int gemmBlocks = (N + 63) / 64;

  // layer 1: x1 = relu(mean(x) @ W1_l + x @ W1_r + b1)
  aggregate_kernel<<<aggBlocks, 256, 0, stream>>>(xh, off, srcs, mh, N);
  gemm_kernel<true, true><<<gemmBlocks, 256, 0, stream>>>(mh, xh, wt1, b1l, x1h, N);
  // layer 2: x2 = relu(mean(x1) @ W2_l + x1 @ W2_r + b2)
  aggregate_kernel<<<aggBlocks, 256, 0, stream>>>(x1h, off, srcs, mh, N);
  gemm_kernel<true, true><<<gemmBlocks, 256, 0, stream>>>(mh, x1h, wt2, b2l, x2h, N);
  // head: out = [x1|x2] @ W_lin + b_lin   (fp32 out)
  gemm_kernel<false, false><<<gemmBlocks, 256, 0, stream>>>(x1h, x2h, wt3, blin, d_out, N);
}

// Round 2
// 343.222 us; speedup vs baseline: 1.1789x; 1.1789x over previous
//
#include <hip/hip_runtime.h>

// GraphSAGE 2-layer + linear head, N=50000, E=600000, C=128 everywhere.
// Pipeline:
//   CSR build (deg -> scan -> fill)   [int atomics only, 600k each]
//   x -> fp16
//   per layer: wave-per-node mean-aggregate (fp32 accum, fp16 in/out)
//              MFMA fp16 GEMM  Y = act([U|V] @ [Wl;Wr]^T-staged + b)
// All matmuls use mfma_f32_16x16x32_f16 with W pre-transposed to [N][K] fp16
// so A and B fragments are single 16B contiguous global loads (no LDS).
// R1: aggregate edge-loop unrolled x4 (4 independent gathers in flight) —
//     R0 showed MfmaUtil=0/VALU=17%/HBM=15% => pure latency-bound serial loads.

typedef _Float16 f16;
typedef __attribute__((ext_vector_type(2))) _Float16 f16x2;
typedef __attribute__((ext_vector_type(4))) _Float16 f16x4;
typedef __attribute__((ext_vector_type(8))) _Float16 f16x8;
typedef __attribute__((ext_vector_type(4))) float f32x4;

__global__ void convert_f32_to_f16(const float* __restrict__ in, f16* __restrict__ out, int n4) {
  int i = blockIdx.x * blockDim.x + threadIdx.x;
  if (i < n4) {
    const float4 v = ((const float4*)in)[i];
    f16x4 h = { (f16)v.x, (f16)v.y, (f16)v.z, (f16)v.w };
    ((f16x4*)out)[i] = h;
  }
}

// wt[n*256 + k] = (k<128 ? WA[k][n] : WB[k-128][n]) as fp16.  [K=256 rows stacked]
__global__ void prep_w(const float* __restrict__ WA, const float* __restrict__ WB,
                       f16* __restrict__ wt) {
  int tid = blockIdx.x * blockDim.x + threadIdx.x;
  if (tid < 256 * 128) {
    int n = tid & 127, k = tid >> 7;
    float v = (k < 128) ? WA[k * 128 + n] : WB[(k - 128) * 128 + n];
    wt[n * 256 + k] = (f16)v;
  }
}

__global__ void deg_kernel(const int* __restrict__ ei, int* __restrict__ deg, int E) {
  int e = blockIdx.x * blockDim.x + threadIdx.x;
  if (e < E) atomicAdd(&deg[ei[E + e]], 1);
}

// exclusive scan, 1024-elem chunks per block (Hillis-Steele, ping-pong LDS)
__global__ void scan_block_kernel(const int* __restrict__ in, int* __restrict__ out,
                                  int* __restrict__ sums, int n) {
  __shared__ int s[2][1024];
  int t = threadIdx.x;
  int gid = blockIdx.x * 1024 + t;
  int v = (gid < n) ? in[gid] : 0;
  int cur = 0;
  s[0][t] = v;
  __syncthreads();
  for (int ofs = 1; ofs < 1024; ofs <<= 1) {
    int nv = s[cur][t] + ((t >= ofs) ? s[cur][t - ofs] : 0);
    s[cur ^ 1][t] = nv;
    cur ^= 1;
    __syncthreads();
  }
  if (gid < n) out[gid] = s[cur][t] - v;      // exclusive within block
  if (t == 1023) sums[blockIdx.x] = s[cur][1023];
}

// single-wave shuffle scan of block sums (nb <= 64; N=50000 -> nb=49)
__global__ void scan_sums_kernel(int* __restrict__ sums, int nb, int* __restrict__ off, int n) {
  int lane = threadIdx.x;
  int orig = (lane < nb) ? sums[lane] : 0;
  int v = orig;
  for (int ofs = 1; ofs < 64; ofs <<= 1) {
    int u = __shfl_up(v, ofs);
    if (lane >= ofs) v += u;
  }
  if (lane < nb) sums[lane] = v - orig;       // exclusive block offsets
  if (lane == nb - 1) off[n] = v;             // total == E
}

__global__ void scan_add_kernel(int* __restrict__ off, const int* __restrict__ sums, int n) {
  int gid = blockIdx.x * 1024 + threadIdx.x;
  if (gid < n) off[gid] += sums[blockIdx.x];
}

__global__ void fill_kernel(const int* __restrict__ ei, const int* __restrict__ off,
                            int* __restrict__ cursor, int* __restrict__ srcs, int E) {
  int e = blockIdx.x * blockDim.x + threadIdx.x;
  if (e < E) {
    int src = ei[e], dst = ei[E + e];
    int pos = atomicAdd(&cursor[dst], 1);
    srcs[off[dst] + pos] = src;
  }
}

// one wave per node: lane handles 2 channels; coalesced 256B row reads.
// Edge loop unrolled x4: 4 independent gathers in flight per iteration.
__global__ void aggregate_kernel(const f16* __restrict__ feat, const int* __restrict__ off,
                                 const int* __restrict__ srcs, f16* __restrict__ meanf, int n) {
  int wid = (int)((blockIdx.x * blockDim.x + threadIdx.x) >> 6);
  int lane = threadIdx.x & 63;
  if (wid >= n) return;
  int beg = off[wid], end = off[wid + 1];
  int c = lane * 2;
  float a0 = 0.f, a1 = 0.f;
  int e = beg;
  for (; e + 4 <= end; e += 4) {
    int s0 = srcs[e], s1 = srcs[e + 1], s2 = srcs[e + 2], s3 = srcs[e + 3];
    f16x2 v0 = *(const f16x2*)(feat + (size_t)s0 * 128 + c);
    f16x2 v1 = *(const f16x2*)(feat + (size_t)s1 * 128 + c);
    f16x2 v2 = *(const f16x2*)(feat + (size_t)s2 * 128 + c);
    f16x2 v3 = *(const f16x2*)(feat + (size_t)s3 * 128 + c);
    a0 += (float)v0.x + (float)v1.x + (float)v2.x + (float)v3.x;
    a1 += (float)v0.y + (float)v1.y + (float)v2.y + (float)v3.y;
  }
  for (; e < end; ++e) {
    int s = srcs[e];
    f16x2 v = *(const f16x2*)(feat + (size_t)s * 128 + c);
    a0 += (float)v.x;
    a1 += (float)v.y;
  }
  float inv = 1.0f / fmaxf((float)(end - beg), 1.0f);
  f16x2 o = { (f16)(a0 * inv), (f16)(a1 * inv) };
  *(f16x2*)(meanf + (size_t)wid * 128 + c) = o;
}

// Y[M,128] = act([U|V][M,256] @ W + bias); W staged transposed as wt[n][k] fp16.
// block = 256 thr = 4 waves; wave computes 16 rows x 128 cols.
// A frag:  lane m=lane&15, k=(lane>>4)*8+j  -> 16B contiguous load from U/V row
// B frag:  lane n=lane&15, k=(lane>>4)*8+j  -> 16B contiguous load from wt row
// C/D:     col=lane&15, row=(lane>>4)*4+reg
template <bool RELU, bool OUT16>
__global__ __launch_bounds__(256) void gemm_kernel(
    const f16* __restrict__ U, const f16* __restrict__ V, const f16* __restrict__ Wt,
    const float* __restrict__ bias, void* __restrict__ outp, int M) {
  int wave = threadIdx.x >> 6;
  int lane = threadIdx.x & 63;
  int m0 = blockIdx.x * 64 + wave * 16;
  int row = m0 + (lane & 15);
  int rowc = row < M ? row : M - 1;   // clamp tail-row loads (stores guarded)
  int kq = (lane >> 4) * 8;
  const f16* baseU = U + (size_t)rowc * 128 + kq;
  const f16* baseV = V + (size_t)rowc * 128 + kq;
  const f16* baseW = Wt + (size_t)(lane & 15) * 256 + kq;
  f32x4 acc[8] = {};
#pragma unroll
  for (int kk = 0; kk < 8; ++kk) {
    const int k0 = kk * 32;
    const f16* ap = (k0 < 128) ? (baseU + k0) : (baseV + (k0 - 128));
    f16x8 a = *(const f16x8*)ap;
#pragma unroll
    for (int t = 0; t < 8; ++t) {
      f16x8 b = *(const f16x8*)(baseW + t * 16 * 256 + k0);
      acc[t] = __builtin_amdgcn_mfma_f32_16x16x32_f16(a, b, acc[t], 0, 0, 0);
    }
  }
  int col = lane & 15;
  int rbase = m0 + (lane >> 4) * 4;
#pragma unroll
  for (int t = 0; t < 8; ++t) {
    float bv = bias[t * 16 + col];
#pragma unroll
    for (int i = 0; i < 4; ++i) {
      int r = rbase + i;
      if (r < M) {
        float v = acc[t][i] + bv;
        if (RELU) v = fmaxf(v, 0.f);
        size_t idx = (size_t)r * 128 + t * 16 + col;
        if (OUT16) ((f16*)outp)[idx] = (f16)v;
        else       ((float*)outp)[idx] = v;
      }
    }
  }
}

extern "C" void kernel_launch(void* const* d_in, const int* in_sizes, int n_in,
                              void* d_out, int out_size, void* d_ws, size_t ws_size,
                              hipStream_t stream) {
  (void)n_in; (void)out_size; (void)ws_size;
  const float* x    = (const float*)d_in[0];
  const int*   ei   = (const int*)d_in[1];
  const float* W1l  = (const float*)d_in[2];
  const float* b1l  = (const float*)d_in[3];
  const float* W1r  = (const float*)d_in[4];
  const float* W2l  = (const float*)d_in[5];
  const float* b2l  = (const float*)d_in[6];
  const float* W2r  = (const float*)d_in[7];
  const float* Wlin = (const float*)d_in[8];
  const float* blin = (const float*)d_in[9];
  const int N = in_sizes[0] / 128;
  const int E = in_sizes[1] / 2;

  char* ws = (char*)d_ws;
  size_t o = 0;
  auto alloc = [&](size_t bytes) {
    char* p = ws + o;
    o = (o + bytes + 255) & ~(size_t)255;
    return p;
  };
  f16* xh   = (f16*)alloc((size_t)N * 128 * 2);
  f16* x1h  = (f16*)alloc((size_t)N * 128 * 2);
  f16* x2h  = (f16*)alloc((size_t)N * 128 * 2);
  f16* mh   = (f16*)alloc((size_t)N * 128 * 2);
  f16* wt1  = (f16*)alloc(256 * 128 * 2);
  f16* wt2  = (f16*)alloc(256 * 128 * 2);
  f16* wt3  = (f16*)alloc(256 * 128 * 2);
  int* deg  = (int*)alloc((size_t)N * 2 * 4);   // deg[N] and cur[N] adjacent: one memset
  int* cur  = deg + N;
  int* off  = (int*)alloc(((size_t)N + 1) * 4);
  int* srcs = (int*)alloc((size_t)E * 4);
  int* sums = (int*)alloc(64 * 4);

  hipMemsetAsync(deg, 0, (size_t)N * 2 * 4, stream);

  const int nb = (N + 1023) / 1024;  // 49 for N=50000 (must be <= 64)
  deg_kernel<<<(E + 255) / 256, 256, 0, stream>>>(ei, deg, E);
  scan_block_kernel<<<nb, 1024, 0, stream>>>(deg, off, sums, N);
  scan_sums_kernel<<<1, 64, 0, stream>>>(sums, nb, off, N);
  scan_add_kernel<<<nb, 1024, 0, stream>>>(off, sums, N);
  fill_kernel<<<(E + 255) / 256, 256, 0, stream>>>(ei, off, cur, srcs, E);

  convert_f32_to_f16<<<((N * 128 / 4) + 255) / 256, 256, 0, stream>>>(x, xh, N * 128 / 4);
  prep_w<<<(256 * 128 + 255) / 256, 256, 0, stream>>>(W1l, W1r, wt1);
  prep_w<<<(256 * 128 + 255) / 256, 256, 0, stream>>>(W2l, W2r, wt2);
  prep_w<<<(256 * 128 + 255) / 256, 256, 0, stream>>>(Wlin, Wlin + 128 * 128, wt3);

  const int aggBlocks  = (N + 3) / 4;    // 4 waves/block, wave per node
  const int gemmBlocks = (N + 63) / 64;

  // layer 1: x1 = relu(mean(x) @ W1_l + x @ W1_r + b1)
  aggregate_kernel<<<aggBlocks, 256, 0, stream>>>(xh, off, srcs, mh, N);
  gemm_kernel<true, true><<<gemmBlocks, 256, 0, stream>>>(mh, xh, wt1, b1l, x1h, N);
  // layer 2: x2 = relu(mean(x1) @ W2_l + x1 @ W2_r + b2)
  aggregate_kernel<<<aggBlocks, 256, 0, stream>>>(x1h, off, srcs, mh, N);
  gemm_kernel<true, true><<<gemmBlocks, 256, 0, stream>>>(mh, x1h, wt2, b2l, x2h, N);
  // head: out = [x1|x2] @ W_lin + b_lin   (fp32 out)
  gemm_kernel<false, false><<<gemmBlocks, 256, 0, stream>>>(x1h, x2h, wt3, blin, d_out, N);
}

// Round 3
// 265.072 us; speedup vs baseline: 1.5264x; 1.2948x over previous
//
#include <hip/hip_runtime.h>

// GraphSAGE 2-layer + linear head, N=50000, E=600000, C=128 everywhere.
// R2: GEMM v2 — Wt staged to LDS (k-chunked layout, linear 64KB copy),
//     32 rows/wave, all 16 A-loads prefetched before the barrier.
//     R1 gemm showed MfmaUtil 2.6%/VALU 2.5%/903GB/s at VGPR=60 => compiler
//     issued loads just-in-time, full L2 latency per k-step.
//     Aggregate v2 — 4 edge-slots/wave x f16x8/lane, x2 unroll (8 gathers in
//     flight), shuffle-reduce across slots.

typedef _Float16 f16;
typedef __attribute__((ext_vector_type(2))) _Float16 f16x2;
typedef __attribute__((ext_vector_type(4))) _Float16 f16x4;
typedef __attribute__((ext_vector_type(8))) _Float16 f16x8;
typedef __attribute__((ext_vector_type(4))) float f32x4;

__global__ void convert_f32_to_f16(const float* __restrict__ in, f16* __restrict__ out, int n4) {
  int i = blockIdx.x * blockDim.x + threadIdx.x;
  if (i < n4) {
    const float4 v = ((const float4*)in)[i];
    f16x4 h = { (f16)v.x, (f16)v.y, (f16)v.z, (f16)v.w };
    ((f16x4*)out)[i] = h;
  }
}

// k-chunked transposed weight: wt[(chunk*128 + n)*8 + j] = W[k=chunk*8+j][n]
// where W = [WA;WB] stacked (K=256). GEMM stages this linearly into LDS and
// reads B frags as 16B ds_read_b128 at ((kk*4+quad)*128 + t*16 + n)*16B.
__global__ void prep_w(const float* __restrict__ WA, const float* __restrict__ WB,
                       f16* __restrict__ wt) {
  int tid = blockIdx.x * blockDim.x + threadIdx.x;
  if (tid < 32768) {
    int j = tid & 7, n = (tid >> 3) & 127, chunk = tid >> 10;
    int k = chunk * 8 + j;
    float v = (k < 128) ? WA[k * 128 + n] : WB[(k - 128) * 128 + n];
    wt[tid] = (f16)v;
  }
}

__global__ void deg_kernel(const int* __restrict__ ei, int* __restrict__ deg, int E) {
  int e = blockIdx.x * blockDim.x + threadIdx.x;
  if (e < E) atomicAdd(&deg[ei[E + e]], 1);
}

// exclusive scan, 1024-elem chunks per block (Hillis-Steele, ping-pong LDS)
__global__ void scan_block_kernel(const int* __restrict__ in, int* __restrict__ out,
                                  int* __restrict__ sums, int n) {
  __shared__ int s[2][1024];
  int t = threadIdx.x;
  int gid = blockIdx.x * 1024 + t;
  int v = (gid < n) ? in[gid] : 0;
  int cur = 0;
  s[0][t] = v;
  __syncthreads();
  for (int ofs = 1; ofs < 1024; ofs <<= 1) {
    int nv = s[cur][t] + ((t >= ofs) ? s[cur][t - ofs] : 0);
    s[cur ^ 1][t] = nv;
    cur ^= 1;
    __syncthreads();
  }
  if (gid < n) out[gid] = s[cur][t] - v;      // exclusive within block
  if (t == 1023) sums[blockIdx.x] = s[cur][1023];
}

// single-wave shuffle scan of block sums (nb <= 64; N=50000 -> nb=49)
__global__ void scan_sums_kernel(int* __restrict__ sums, int nb, int* __restrict__ off, int n) {
  int lane = threadIdx.x;
  int orig = (lane < nb) ? sums[lane] : 0;
  int v = orig;
  for (int ofs = 1; ofs < 64; ofs <<= 1) {
    int u = __shfl_up(v, ofs);
    if (lane >= ofs) v += u;
  }
  if (lane < nb) sums[lane] = v - orig;       // exclusive block offsets
  if (lane == nb - 1) off[n] = v;             // total == E
}

__global__ void scan_add_kernel(int* __restrict__ off, const int* __restrict__ sums, int n) {
  int gid = blockIdx.x * 1024 + threadIdx.x;
  if (gid < n) off[gid] += sums[blockIdx.x];
}

__global__ void fill_kernel(const int* __restrict__ ei, const int* __restrict__ off,
                            int* __restrict__ cursor, int* __restrict__ srcs, int E) {
  int e = blockIdx.x * blockDim.x + threadIdx.x;
  if (e < E) {
    int src = ei[e], dst = ei[E + e];
    int pos = atomicAdd(&cursor[dst], 1);
    srcs[off[dst] + pos] = src;
  }
}

// wave per node; lane = slot(4)x16 + chgroup(16). Each slot handles one edge,
// lane loads f16x8 (16B) of that edge's row => 4 edges (1KB) per group, x2
// unrolled => 8 gathers in flight. Cross-slot shuffle reduce at the end.
__global__ void aggregate_kernel(const f16* __restrict__ feat, const int* __restrict__ off,
                                 const int* __restrict__ srcs, f16* __restrict__ meanf, int n) {
  int wid = (int)((blockIdx.x * blockDim.x + threadIdx.x) >> 6);
  int lane = threadIdx.x & 63;
  if (wid >= n) return;
  int sub = lane >> 4, n15 = lane & 15;
  int beg = off[wid], end = off[wid + 1];
  int deg = end - beg;
  float acc[8] = {};
  int e = beg;
  int bulkEnd = beg + (deg & ~7);
  for (; e < bulkEnd; e += 8) {
    int sA = srcs[e + sub];
    int sB = srcs[e + 4 + sub];
    f16x8 vA = *(const f16x8*)(feat + (size_t)sA * 128 + n15 * 8);
    f16x8 vB = *(const f16x8*)(feat + (size_t)sB * 128 + n15 * 8);
#pragma unroll
    for (int j = 0; j < 8; ++j) acc[j] += (float)vA[j] + (float)vB[j];
  }
  int rem = end - e;
  if (sub < rem) {
    int s = srcs[e + sub];
    f16x8 v = *(const f16x8*)(feat + (size_t)s * 128 + n15 * 8);
#pragma unroll
    for (int j = 0; j < 8; ++j) acc[j] += (float)v[j];
  }
  if (sub + 4 < rem) {
    int s = srcs[e + 4 + sub];
    f16x8 v = *(const f16x8*)(feat + (size_t)s * 128 + n15 * 8);
#pragma unroll
    for (int j = 0; j < 8; ++j) acc[j] += (float)v[j];
  }
#pragma unroll
  for (int j = 0; j < 8; ++j) {
    acc[j] += __shfl_xor(acc[j], 16);
    acc[j] += __shfl_xor(acc[j], 32);
  }
  if (sub == 0) {
    float inv = 1.0f / fmaxf((float)deg, 1.0f);
    f16x8 o;
#pragma unroll
    for (int j = 0; j < 8; ++j) o[j] = (f16)(acc[j] * inv);
    *(f16x8*)(meanf + (size_t)wid * 128 + n15 * 8) = o;
  }
}

// Y[M,128] = act([U|V][M,256] @ W + bias); Wt in k-chunked layout (see prep_w).
// block = 256 thr = 4 waves; wave computes 32 rows x 128 cols (128 rows/block).
// All 16 A-frag loads issued before the staging barrier; B frags from LDS.
// A frag:  lane m=n15, k=quad*8+j  (f16x8 from U/V row)
// B frag:  lds[(kk*4+quad)*128 + t*16 + n15]  (16B unit)
// C/D:     col=n15, row=quad*4+reg
template <bool RELU, bool OUT16>
__global__ __launch_bounds__(256, 2) void gemm_kernel(
    const f16* __restrict__ U, const f16* __restrict__ V, const f16* __restrict__ Wt,
    const float* __restrict__ bias, void* __restrict__ outp, int M) {
  __shared__ f16 ldsb[32768];   // 64 KB
  int tid = threadIdx.x;
  int wave = tid >> 6, lane = tid & 63;
  int quad = lane >> 4, n15 = lane & 15;
  int m0 = blockIdx.x * 128 + wave * 32;
  int kq = quad * 8;

  // prefetch ALL A fragments (2 m-frags x 8 k-steps = 16 x 16B loads in flight)
  f16x8 a[2][8];
#pragma unroll
  for (int r = 0; r < 2; ++r) {
    int row = m0 + r * 16 + n15;
    int rowc = row < M ? row : M - 1;   // clamp tail loads (stores guarded)
    const f16* bu = U + (size_t)rowc * 128 + kq;
    const f16* bv = V + (size_t)rowc * 128 + kq;
#pragma unroll
    for (int kk = 0; kk < 4; ++kk) a[r][kk] = *(const f16x8*)(bu + kk * 32);
#pragma unroll
    for (int kk = 4; kk < 8; ++kk) a[r][kk] = *(const f16x8*)(bv + (kk - 4) * 32);
  }

  // stage Wt -> LDS: linear 64KB copy, coalesced reads, lane-linear writes
#pragma unroll
  for (int it = 0; it < 16; ++it) {
    int idx = it * 256 + tid;
    ((f16x8*)ldsb)[idx] = ((const f16x8*)Wt)[idx];
  }
  __syncthreads();

  f32x4 acc[2][8] = {};
#pragma unroll
  for (int kk = 0; kk < 8; ++kk) {
#pragma unroll
    for (int t = 0; t < 8; ++t) {
      f16x8 b = ((const f16x8*)ldsb)[(kk * 4 + quad) * 128 + t * 16 + n15];
#pragma unroll
      for (int r = 0; r < 2; ++r)
        acc[r][t] = __builtin_amdgcn_mfma_f32_16x16x32_f16(a[r][kk], b, acc[r][t], 0, 0, 0);
    }
  }

  int rbase0 = m0 + quad * 4;
#pragma unroll
  for (int t = 0; t < 8; ++t) {
    float bv = bias[t * 16 + n15];
#pragma unroll
    for (int r = 0; r < 2; ++r) {
#pragma unroll
      for (int i = 0; i < 4; ++i) {
        int row = rbase0 + r * 16 + i;
        if (row < M) {
          float v = acc[r][t][i] + bv;
          if (RELU) v = fmaxf(v, 0.f);
          size_t idx = (size_t)row * 128 + t * 16 + n15;
          if (OUT16) ((f16*)outp)[idx] = (f16)v;
          else       ((float*)outp)[idx] = v;
        }
      }
    }
  }
}

extern "C" void kernel_launch(void* const* d_in, const int* in_sizes, int n_in,
                              void* d_out, int out_size, void* d_ws, size_t ws_size,
                              hipStream_t stream) {
  (void)n_in; (void)out_size; (void)ws_size;
  const float* x    = (const float*)d_in[0];
  const int*   ei   = (const int*)d_in[1];
  const float* W1l  = (const float*)d_in[2];
  const float* b1l  = (const float*)d_in[3];
  const float* W1r  = (const float*)d_in[4];
  const float* W2l  = (const float*)d_in[5];
  const float* b2l  = (const float*)d_in[6];
  const float* W2r  = (const float*)d_in[7];
  const float* Wlin = (const float*)d_in[8];
  const float* blin = (const float*)d_in[9];
  const int N = in_sizes[0] / 128;
  const int E = in_sizes[1] / 2;

  char* ws = (char*)d_ws;
  size_t o = 0;
  auto alloc = [&](size_t bytes) {
    char* p = ws + o;
    o = (o + bytes + 255) & ~(size_t)255;
    return p;
  };
  f16* xh   = (f16*)alloc((size_t)N * 128 * 2);
  f16* x1h  = (f16*)alloc((size_t)N * 128 * 2);
  f16* x2h  = (f16*)alloc((size_t)N * 128 * 2);
  f16* mh   = (f16*)alloc((size_t)N * 128 * 2);
  f16* wt1  = (f16*)alloc(32768 * 2);
  f16* wt2  = (f16*)alloc(32768 * 2);
  f16* wt3  = (f16*)alloc(32768 * 2);
  int* deg  = (int*)alloc((size_t)N * 2 * 4);   // deg[N] and cur[N]: one memset
  int* cur  = deg + N;
  int* off  = (int*)alloc(((size_t)N + 1) * 4);
  int* srcs = (int*)alloc((size_t)E * 4);
  int* sums = (int*)alloc(64 * 4);

  hipMemsetAsync(deg, 0, (size_t)N * 2 * 4, stream);

  const int nb = (N + 1023) / 1024;  // 49 for N=50000 (must be <= 64)
  deg_kernel<<<(E + 255) / 256, 256, 0, stream>>>(ei, deg, E);
  scan_block_kernel<<<nb, 1024, 0, stream>>>(deg, off, sums, N);
  scan_sums_kernel<<<1, 64, 0, stream>>>(sums, nb, off, N);
  scan_add_kernel<<<nb, 1024, 0, stream>>>(off, sums, N);
  fill_kernel<<<(E + 255) / 256, 256, 0, stream>>>(ei, off, cur, srcs, E);

  convert_f32_to_f16<<<((N * 128 / 4) + 255) / 256, 256, 0, stream>>>(x, xh, N * 128 / 4);
  prep_w<<<128, 256, 0, stream>>>(W1l, W1r, wt1);
  prep_w<<<128, 256, 0, stream>>>(W2l, W2r, wt2);
  prep_w<<<128, 256, 0, stream>>>(Wlin, Wlin + 128 * 128, wt3);

  const int aggBlocks  = (N + 3) / 4;      // 4 waves/block, wave per node
  const int gemmBlocks = (N + 127) / 128;  // 128 rows/block

  // layer 1: x1 = relu(mean(x) @ W1_l + x @ W1_r + b1)
  aggregate_kernel<<<aggBlocks, 256, 0, stream>>>(xh, off, srcs, mh, N);
  gemm_kernel<true, true><<<gemmBlocks, 256, 0, stream>>>(mh, xh, wt1, b1l, x1h, N);
  // layer 2: x2 = relu(mean(x1) @ W2_l + x1 @ W2_r + b2)
  aggregate_kernel<<<aggBlocks, 256, 0, stream>>>(x1h, off, srcs, mh, N);
  gemm_kernel<true, true><<<gemmBlocks, 256, 0, stream>>>(mh, x1h, wt2, b2l, x2h, N);
  // head: out = [x1|x2] @ W_lin + b_lin   (fp32 out)
  gemm_kernel<false, false><<<gemmBlocks, 256, 0, stream>>>(x1h, x2h, wt3, blin, d_out, N);
}

// Round 4
// 260.580 us; speedup vs baseline: 1.5528x; 1.0172x over previous
//
#include <hip/hip_runtime.h>

// GraphSAGE 2-layer + linear head, N=50000, E=600000, C=128 everywhere.
// R3: aggregate v3 — prefetch ALL srcs idx (<=24 edges/node) then ALL gathers
//     (up to 12 x 1KB in flight, single wait) , 2 nodes per wave; fused
//     prep kernel (f32->f16 convert + degree count + 3x weight transpose);
//     scan_sums folded into scan_add (49-block redundant wave-reduce).
//     R2 evidence: agg slot-version neutral (still wait-per-round); all
//     kernels now < fillBuffer's 43us; cut latency round-trips + launches.

typedef _Float16 f16;
typedef __attribute__((ext_vector_type(2))) _Float16 f16x2;
typedef __attribute__((ext_vector_type(4))) _Float16 f16x4;
typedef __attribute__((ext_vector_type(8))) _Float16 f16x8;
typedef __attribute__((ext_vector_type(4))) float f32x4;

// ---- fused prep: [0,cb) convert x->f16 | [cb,cb+db) degree | rest: weights
// weights stored k-chunked transposed, 3 tables contiguous (32768 f16 each):
// wt[w][(chunk*128 + n)*8 + j] = W_w[k=chunk*8+j][n], W = [WA;WB] stacked.
__global__ void prep_kernel(const float* __restrict__ x, f16* __restrict__ xh, int n4,
                            const int* __restrict__ ei, int* __restrict__ deg, int E,
                            const float* __restrict__ W1l, const float* __restrict__ W1r,
                            const float* __restrict__ W2l, const float* __restrict__ W2r,
                            const float* __restrict__ Wlin, f16* __restrict__ wt,
                            int cb, int db) {
  int b = blockIdx.x;
  if (b < cb) {
    int i = b * 256 + threadIdx.x;
    if (i < n4) {
      const float4 v = ((const float4*)x)[i];
      f16x4 h = { (f16)v.x, (f16)v.y, (f16)v.z, (f16)v.w };
      ((f16x4*)xh)[i] = h;
    }
  } else if (b < cb + db) {
    int e = (b - cb) * 256 + threadIdx.x;
    if (e < E) atomicAdd(&deg[ei[E + e]], 1);
  } else {
    int tid = (b - cb - db) * 256 + threadIdx.x;   // 0 .. 3*32768
    int w = tid >> 15, idx = tid & 32767;
    int j = idx & 7, n = (idx >> 3) & 127, chunk = idx >> 10;
    int k = chunk * 8 + j;
    float v;
    if (w == 0) v = (k < 128) ? W1l[k * 128 + n] : W1r[(k - 128) * 128 + n];
    else if (w == 1) v = (k < 128) ? W2l[k * 128 + n] : W2r[(k - 128) * 128 + n];
    else v = Wlin[k * 128 + n];
    wt[tid] = (f16)v;
  }
}

// exclusive scan, 1024-elem chunks per block (Hillis-Steele, ping-pong LDS)
__global__ void scan_block_kernel(const int* __restrict__ in, int* __restrict__ out,
                                  int* __restrict__ sums, int n) {
  __shared__ int s[2][1024];
  int t = threadIdx.x;
  int gid = blockIdx.x * 1024 + t;
  int v = (gid < n) ? in[gid] : 0;
  int cur = 0;
  s[0][t] = v;
  __syncthreads();
  for (int ofs = 1; ofs < 1024; ofs <<= 1) {
    int nv = s[cur][t] + ((t >= ofs) ? s[cur][t - ofs] : 0);
    s[cur ^ 1][t] = nv;
    cur ^= 1;
    __syncthreads();
  }
  if (gid < n) out[gid] = s[cur][t] - v;      // exclusive within block
  if (t == 1023) sums[blockIdx.x] = s[cur][1023];
}

// adds prefix of block sums (each block redundantly reduces sums[0..b), nb<=64),
// zeroes cur[], writes off[n]=E.  Replaces scan_sums + scan_add + cur-memset.
__global__ void scan_add_kernel(int* __restrict__ off, const int* __restrict__ sums,
                                int* __restrict__ cur, int n, int E) {
  __shared__ int prefix_s;
  int b = blockIdx.x;
  if (threadIdx.x < 64) {
    int v = ((int)threadIdx.x < b) ? sums[threadIdx.x] : 0;
#pragma unroll
    for (int ofs = 1; ofs < 64; ofs <<= 1) v += __shfl_xor(v, ofs);
    if (threadIdx.x == 0) prefix_s = v;
  }
  __syncthreads();
  int gid = b * 1024 + threadIdx.x;
  if (gid < n) { off[gid] += prefix_s; cur[gid] = 0; }
  if (gid == 0) off[n] = E;
}

__global__ void fill_kernel(const int* __restrict__ ei, const int* __restrict__ off,
                            int* __restrict__ cursor, int* __restrict__ srcs, int E) {
  int e = blockIdx.x * blockDim.x + threadIdx.x;
  if (e < E) {
    int src = ei[e], dst = ei[E + e];
    int pos = atomicAdd(&cursor[dst], 1);
    srcs[off[dst] + pos] = src;
  }
}

// v3: wave handles TWO nodes. lane = slot(sub=lane>>4) x chgroup(n15).
// Prefetch up to 6 rounds x 4 slots = 24 edge indices per node (independent
// broadcast loads), then issue ALL gathers (<=12 x 16B/lane in flight, one
// wait), then accumulate. deg>24 tail: slot-round loop (rare, Poisson(12)).
#define AGG_R 6
__global__ void aggregate_kernel(const f16* __restrict__ feat, const int* __restrict__ off,
                                 const int* __restrict__ srcs, f16* __restrict__ meanf, int n) {
  int pair = (int)((blockIdx.x * blockDim.x + threadIdx.x) >> 6);
  int w0 = pair * 2;
  if (w0 >= n) return;
  int w1 = w0 + 1;
  int lane = threadIdx.x & 63;
  int sub = lane >> 4, n15 = lane & 15;
  int beg0 = off[w0], end0 = off[w0 + 1];
  int beg1 = end0;                              // CSR contiguity
  int end1 = (w1 < n) ? off[w1 + 1] : end0;
  int deg0 = end0 - beg0, deg1 = end1 - beg1;

  // phase 1: prefetch srcs indices (all loads independent)
  int s0[AGG_R], s1[AGG_R];
  bool v0[AGG_R], v1[AGG_R];
#pragma unroll
  for (int k = 0; k < AGG_R; ++k) {
    int p = 4 * k + sub;
    v0[k] = p < deg0;  s0[k] = v0[k] ? srcs[beg0 + p] : 0;
    v1[k] = p < deg1;  s1[k] = v1[k] ? srcs[beg1 + p] : 0;
  }
  // phase 2: issue all gathers
  f16x8 g0[AGG_R], g1[AGG_R];
#pragma unroll
  for (int k = 0; k < AGG_R; ++k) {
    if (v0[k]) g0[k] = *(const f16x8*)(feat + (size_t)s0[k] * 128 + n15 * 8);
    if (v1[k]) g1[k] = *(const f16x8*)(feat + (size_t)s1[k] * 128 + n15 * 8);
  }
  // phase 3: accumulate
  float acc0[8] = {}, acc1[8] = {};
#pragma unroll
  for (int k = 0; k < AGG_R; ++k) {
    if (v0[k]) {
#pragma unroll
      for (int j = 0; j < 8; ++j) acc0[j] += (float)g0[k][j];
    }
    if (v1[k]) {
#pragma unroll
      for (int j = 0; j < 8; ++j) acc1[j] += (float)g1[k][j];
    }
  }
  // rare tail: degree > 24
  for (int e = beg0 + 4 * AGG_R; e < end0; e += 4) {
    if (sub < end0 - e) {
      int s = srcs[e + sub];
      f16x8 g = *(const f16x8*)(feat + (size_t)s * 128 + n15 * 8);
#pragma unroll
      for (int j = 0; j < 8; ++j) acc0[j] += (float)g[j];
    }
  }
  for (int e = beg1 + 4 * AGG_R; e < end1; e += 4) {
    if (sub < end1 - e) {
      int s = srcs[e + sub];
      f16x8 g = *(const f16x8*)(feat + (size_t)s * 128 + n15 * 8);
#pragma unroll
      for (int j = 0; j < 8; ++j) acc1[j] += (float)g[j];
    }
  }
  // cross-slot reduce (full, so every sub holds the total)
#pragma unroll
  for (int j = 0; j < 8; ++j) {
    acc0[j] += __shfl_xor(acc0[j], 16);
    acc0[j] += __shfl_xor(acc0[j], 32);
    acc1[j] += __shfl_xor(acc1[j], 16);
    acc1[j] += __shfl_xor(acc1[j], 32);
  }
  if (sub == 0) {
    float inv = 1.0f / fmaxf((float)deg0, 1.0f);
    f16x8 o;
#pragma unroll
    for (int j = 0; j < 8; ++j) o[j] = (f16)(acc0[j] * inv);
    *(f16x8*)(meanf + (size_t)w0 * 128 + n15 * 8) = o;
  } else if (sub == 1 && w1 < n) {
    float inv = 1.0f / fmaxf((float)deg1, 1.0f);
    f16x8 o;
#pragma unroll
    for (int j = 0; j < 8; ++j) o[j] = (f16)(acc1[j] * inv);
    *(f16x8*)(meanf + (size_t)w1 * 128 + n15 * 8) = o;
  }
}

// Y[M,128] = act([U|V][M,256] @ W + bias); Wt in k-chunked layout (see prep).
// block = 256 thr = 4 waves; wave computes 32 rows x 128 cols (128 rows/block).
// All 16 A-frag loads issued before the staging barrier; B frags from LDS.
template <bool RELU, bool OUT16>
__global__ __launch_bounds__(256, 2) void gemm_kernel(
    const f16* __restrict__ U, const f16* __restrict__ V, const f16* __restrict__ Wt,
    const float* __restrict__ bias, void* __restrict__ outp, int M) {
  __shared__ f16 ldsb[32768];   // 64 KB
  int tid = threadIdx.x;
  int wave = tid >> 6, lane = tid & 63;
  int quad = lane >> 4, n15 = lane & 15;
  int m0 = blockIdx.x * 128 + wave * 32;
  int kq = quad * 8;

  // prefetch ALL A fragments (2 m-frags x 8 k-steps = 16 x 16B loads in flight)
  f16x8 a[2][8];
#pragma unroll
  for (int r = 0; r < 2; ++r) {
    int row = m0 + r * 16 + n15;
    int rowc = row < M ? row : M - 1;   // clamp tail loads (stores guarded)
    const f16* bu = U + (size_t)rowc * 128 + kq;
    const f16* bv = V + (size_t)rowc * 128 + kq;
#pragma unroll
    for (int kk = 0; kk < 4; ++kk) a[r][kk] = *(const f16x8*)(bu + kk * 32);
#pragma unroll
    for (int kk = 4; kk < 8; ++kk) a[r][kk] = *(const f16x8*)(bv + (kk - 4) * 32);
  }

  // stage Wt -> LDS: linear 64KB copy, coalesced reads, lane-linear writes
#pragma unroll
  for (int it = 0; it < 16; ++it) {
    int idx = it * 256 + tid;
    ((f16x8*)ldsb)[idx] = ((const f16x8*)Wt)[idx];
  }
  __syncthreads();

  f32x4 acc[2][8] = {};
#pragma unroll
  for (int kk = 0; kk < 8; ++kk) {
#pragma unroll
    for (int t = 0; t < 8; ++t) {
      f16x8 b = ((const f16x8*)ldsb)[(kk * 4 + quad) * 128 + t * 16 + n15];
#pragma unroll
      for (int r = 0; r < 2; ++r)
        acc[r][t] = __builtin_amdgcn_mfma_f32_16x16x32_f16(a[r][kk], b, acc[r][t], 0, 0, 0);
    }
  }

  int rbase0 = m0 + quad * 4;
#pragma unroll
  for (int t = 0; t < 8; ++t) {
    float bv = bias[t * 16 + n15];
#pragma unroll
    for (int r = 0; r < 2; ++r) {
#pragma unroll
      for (int i = 0; i < 4; ++i) {
        int row = rbase0 + r * 16 + i;
        if (row < M) {
          float v = acc[r][t][i] + bv;
          if (RELU) v = fmaxf(v, 0.f);
          size_t idx = (size_t)row * 128 + t * 16 + n15;
          if (OUT16) ((f16*)outp)[idx] = (f16)v;
          else       ((float*)outp)[idx] = v;
        }
      }
    }
  }
}

extern "C" void kernel_launch(void* const* d_in, const int* in_sizes, int n_in,
                              void* d_out, int out_size, void* d_ws, size_t ws_size,
                              hipStream_t stream) {
  (void)n_in; (void)out_size; (void)ws_size;
  const float* x    = (const float*)d_in[0];
  const int*   ei   = (const int*)d_in[1];
  const float* W1l  = (const float*)d_in[2];
  const float* b1l  = (const float*)d_in[3];
  const float* W1r  = (const float*)d_in[4];
  const float* W2l  = (const float*)d_in[5];
  const float* b2l  = (const float*)d_in[6];
  const float* W2r  = (const float*)d_in[7];
  const float* Wlin = (const float*)d_in[8];
  const float* blin = (const float*)d_in[9];
  const int N = in_sizes[0] / 128;
  const int E = in_sizes[1] / 2;

  char* ws = (char*)d_ws;
  size_t o = 0;
  auto alloc = [&](size_t bytes) {
    char* p = ws + o;
    o = (o + bytes + 255) & ~(size_t)255;
    return p;
  };
  f16* xh   = (f16*)alloc((size_t)N * 128 * 2);
  f16* x1h  = (f16*)alloc((size_t)N * 128 * 2);
  f16* x2h  = (f16*)alloc((size_t)N * 128 * 2);
  f16* mh   = (f16*)alloc((size_t)N * 128 * 2);
  f16* wt   = (f16*)alloc((size_t)3 * 32768 * 2);   // wt1|wt2|wt3 contiguous
  int* deg  = (int*)alloc((size_t)N * 4);
  int* cur  = (int*)alloc((size_t)N * 4);
  int* off  = (int*)alloc(((size_t)N + 1) * 4);
  int* srcs = (int*)alloc((size_t)E * 4);
  int* sums = (int*)alloc(64 * 4);
  f16* wt1 = wt, *wt2 = wt + 32768, *wt3 = wt + 65536;

  hipMemsetAsync(deg, 0, (size_t)N * 4, stream);

  const int n4 = N * 128 / 4;
  const int cb = (n4 + 255) / 256;           // convert blocks
  const int db = (E + 255) / 256;            // degree blocks
  const int wb = (3 * 32768) / 256;          // weight blocks
  prep_kernel<<<cb + db + wb, 256, 0, stream>>>(x, xh, n4, ei, deg, E,
                                                W1l, W1r, W2l, W2r, Wlin, wt, cb, db);

  const int nb = (N + 1023) / 1024;  // 49 for N=50000 (must be <= 64)
  scan_block_kernel<<<nb, 1024, 0, stream>>>(deg, off, sums, N);
  scan_add_kernel<<<nb, 1024, 0, stream>>>(off, sums, cur, N, E);
  fill_kernel<<<db, 256, 0, stream>>>(ei, off, cur, srcs, E);

  const int aggBlocks  = ((N + 1) / 2 + 3) / 4;  // 2 nodes/wave, 4 waves/block
  const int gemmBlocks = (N + 127) / 128;        // 128 rows/block

  // layer 1: x1 = relu(mean(x) @ W1_l + x @ W1_r + b1)
  aggregate_kernel<<<aggBlocks, 256, 0, stream>>>(xh, off, srcs, mh, N);
  gemm_kernel<true, true><<<gemmBlocks, 256, 0, stream>>>(mh, xh, wt1, b1l, x1h, N);
  // layer 2: x2 = relu(mean(x1) @ W2_l + x1 @ W2_r + b2)
  aggregate_kernel<<<aggBlocks, 256, 0, stream>>>(x1h, off, srcs, mh, N);
  gemm_kernel<true, true><<<gemmBlocks, 256, 0, stream>>>(mh, x1h, wt2, b2l, x2h, N);
  // head: out = [x1|x2] @ W_lin + b_lin   (fp32 out)
  gemm_kernel<false, false><<<gemmBlocks, 256, 0, stream>>>(x1h, x2h, wt3, blin, d_out, N);
}